// Round 5
// baseline (362.882 us; speedup 1.0000x reference)
//
#include <hip/hip_runtime.h>
#include <stdint.h>

#define NN 100000
#define NE 1600000
#define CH 128
#define OC 64
#define NG 512
#define NBLK 256      // partition blocks
#define NBMAX 4096    // max coarse buckets (nodes/256)

typedef unsigned int uint;
typedef unsigned short ushort;
typedef __attribute__((ext_vector_type(8))) short short8;
typedef __attribute__((ext_vector_type(4))) float floatx4;

__device__ __forceinline__ ushort f2bf(float f) {
    uint u = __float_as_uint(f);
    uint r = u + 0x7fffu + ((u >> 16) & 1u);  // round-to-nearest-even
    return (ushort)(r >> 16);
}
__device__ __forceinline__ float bf_lo(uint g) { return __uint_as_float(g << 16); }
__device__ __forceinline__ float bf_hi(uint g) { return __uint_as_float(g & 0xffff0000u); }

// ---------------- bucket histogram, written bucket-major ----------------
__global__ __launch_bounds__(256) void k_hist(const int* __restrict__ dst,
                                              int* __restrict__ bhT,
                                              int E, int NB, int chunk) {
    __shared__ int h[NBMAX];
    int blk = blockIdx.x, tid = threadIdx.x;
    for (int j = tid; j < NB; j += 256) h[j] = 0;
    __syncthreads();
    int lo = blk * chunk, hi = min(E, lo + chunk);
    for (int i = lo + tid; i < hi; i += 256) atomicAdd(&h[dst[i] >> 8], 1);
    __syncthreads();
    for (int j = tid; j < NB; j += 256) bhT[j * NBLK + blk] = h[j];
}

// ---------------- prefix scan (3-phase, 1024 elems/block) ----------------
__global__ __launch_bounds__(256) void k_scan1(const int* __restrict__ in,
                                               int* __restrict__ excl,
                                               int* __restrict__ bsums, int T) {
    __shared__ int sd[256];
    int tid = threadIdx.x;
    int base = blockIdx.x * 1024 + tid * 4;
    int v[4];
#pragma unroll
    for (int i = 0; i < 4; i++) v[i] = (base + i < T) ? in[base + i] : 0;
    int tsum = v[0] + v[1] + v[2] + v[3];
    int val = tsum;
    sd[tid] = val; __syncthreads();
    for (int off = 1; off < 256; off <<= 1) {
        int t = (tid >= off) ? sd[tid - off] : 0;
        __syncthreads();
        val += t; sd[tid] = val;
        __syncthreads();
    }
    int run = val - tsum;
#pragma unroll
    for (int i = 0; i < 4; i++) {
        if (base + i < T) excl[base + i] = run;
        run += v[i];
    }
    if (tid == 255) bsums[blockIdx.x] = val;
}

__global__ __launch_bounds__(128) void k_scan2(int* __restrict__ bs, int nb) {
    __shared__ int sd[128];
    int tid = threadIdx.x;
    int v = (tid < nb) ? bs[tid] : 0;
    int val = v;
    sd[tid] = val; __syncthreads();
    for (int off = 1; off < 128; off <<= 1) {
        int t = (tid >= off) ? sd[tid - off] : 0;
        __syncthreads();
        val += t; sd[tid] = val;
        __syncthreads();
    }
    if (tid < nb) bs[tid] = val - v;
}

__global__ __launch_bounds__(256) void k_scan3(int* __restrict__ excl,
                                               const int* __restrict__ boff, int T) {
    int i = blockIdx.x * 256 + threadIdx.x;
    if (i < T) excl[i] += boff[i >> 10];
}

// ------- partition: packed (src<<8)|(dst&255) into per-(bucket,block) segs ----
__global__ __launch_bounds__(256) void k_part(const int* __restrict__ src,
                                              const int* __restrict__ dst,
                                              const int* __restrict__ off,
                                              int* __restrict__ ebuf,
                                              int E, int NB, int chunk) {
    __shared__ int cur[NBMAX];
    int blk = blockIdx.x, tid = threadIdx.x;
    for (int j = tid; j < NB; j += 256) cur[j] = off[j * NBLK + blk];
    __syncthreads();
    int lo = blk * chunk, hi = min(E, lo + chunk);
    for (int i = lo + tid; i < hi; i += 256) {
        int s = src[i], d = dst[i];
        int pos = atomicAdd(&cur[d >> 8], 1);
        ebuf[pos] = (s << 8) | (d & 255);
    }
}

// ------- CSR finalize per bucket: deg, dinv, row_start, local scatter -------
__global__ __launch_bounds__(256) void k_csr(const int* __restrict__ ebuf,
                                             const int* __restrict__ off,
                                             int* __restrict__ row_start,
                                             float* __restrict__ dinv,
                                             int* __restrict__ ssrc,
                                             int n, int NB, int E) {
    __shared__ int cnt[256], sc[256], cur[256];
    int b = blockIdx.x, tid = threadIdx.x;
    int node0 = b << 8;
    int bstart = off[b * NBLK];
    int bend = (b + 1 < NB) ? off[(b + 1) * NBLK] : E;
    cnt[tid] = 0;
    __syncthreads();
    for (int i = bstart + tid; i < bend; i += 256)
        atomicAdd(&cnt[ebuf[i] & 255], 1);
    __syncthreads();
    int v = cnt[tid];
    int val = v;
    sc[tid] = val; __syncthreads();
    for (int o = 1; o < 256; o <<= 1) {
        int t = (tid >= o) ? sc[tid - o] : 0;
        __syncthreads();
        val += t; sc[tid] = val;
        __syncthreads();
    }
    int excl = val - v;
    int node = node0 + tid;
    if (node < n) {
        row_start[node] = bstart + excl;
        dinv[node] = rsqrtf((float)v + 1.0f);
    }
    cur[tid] = bstart + excl;
    if (b == NB - 1 && tid == 0) row_start[n] = E;
    __syncthreads();
    for (int i = bstart + tid; i < bend; i += 256) {
        int e = ebuf[i];
        int pos = atomicAdd(&cur[e & 255], 1);
        ssrc[pos] = e >> 8;        // s < 2^23, sign-safe
    }
}

// ---------------- fp32 -> bf16 convert with dinv pre-scale ----------------
__global__ __launch_bounds__(256) void k_cvt(const float* __restrict__ x,
                                             const float* __restrict__ dinv,
                                             ushort* __restrict__ xb, int total) {
    int i = (blockIdx.x * 256 + threadIdx.x) * 4;
    if (i >= total) return;
    float d = dinv[i >> 7];
    float4 v = *(const float4*)(x + i);
    uint2 o;
    o.x = (uint)f2bf(v.x * d) | ((uint)f2bf(v.y * d) << 16);
    o.y = (uint)f2bf(v.z * d) | ((uint)f2bf(v.w * d) << 16);
    *(uint2*)(xb + i) = o;
}

// ---------------- W1 fp32 [k][n] -> Wt bf16 [n][k] ----------------
__global__ __launch_bounds__(256) void k_cvtw(const float* __restrict__ W,
                                              ushort* __restrict__ Wt) {
    int t = blockIdx.x * 256 + threadIdx.x;   // 16384
    int nc = t >> 7, k = t & 127;
    Wt[nc * CH + k] = f2bf(W[k * CH + nc]);
}

// ------- aggregation: out = dinv_dst * (sum_e Hs[src_e] + Hs[dst]) -------
// uint2/lane, half-wave edge split: 16 edges in flight per wave.
__global__ __launch_bounds__(256) void k_agg(const ushort* __restrict__ Hs,
                                             const int* __restrict__ rs,
                                             const int* __restrict__ ssrc,
                                             const float* __restrict__ dinv,
                                             ushort* __restrict__ out, int n) {
    int wid = (blockIdx.x << 2) | (threadIdx.x >> 6);
    if (wid >= n) return;
    int uw = __builtin_amdgcn_readfirstlane(wid);
    int lane = threadIdx.x & 63;
    int half = lane >> 5;
    int li = lane & 31;
    int c = li * 4;                       // 4 bf16 channels per lane
    float a0 = 0.f, a1 = 0.f, a2 = 0.f, a3 = 0.f;
    if (half == 0) {
        uint2 sv = *(const uint2*)(Hs + uw * CH + c);
        a0 = bf_lo(sv.x); a1 = bf_hi(sv.x);
        a2 = bf_lo(sv.y); a3 = bf_hi(sv.y);
    }
    int e0 = rs[uw], e1 = rs[uw + 1];
    int e = e0;
    int m16 = e0 + ((e1 - e0) & ~15);
    for (; e < m16; e += 16) {
        int eb = e + half * 8;
        int s0 = ssrc[eb + 0], s1 = ssrc[eb + 1], s2 = ssrc[eb + 2], s3 = ssrc[eb + 3];
        int s4 = ssrc[eb + 4], s5 = ssrc[eb + 5], s6 = ssrc[eb + 6], s7 = ssrc[eb + 7];
        uint2 g0 = *(const uint2*)(Hs + (s0 << 7) + c);
        uint2 g1 = *(const uint2*)(Hs + (s1 << 7) + c);
        uint2 g2 = *(const uint2*)(Hs + (s2 << 7) + c);
        uint2 g3 = *(const uint2*)(Hs + (s3 << 7) + c);
        uint2 g4 = *(const uint2*)(Hs + (s4 << 7) + c);
        uint2 g5 = *(const uint2*)(Hs + (s5 << 7) + c);
        uint2 g6 = *(const uint2*)(Hs + (s6 << 7) + c);
        uint2 g7 = *(const uint2*)(Hs + (s7 << 7) + c);
        a0 += bf_lo(g0.x) + bf_lo(g1.x) + bf_lo(g2.x) + bf_lo(g3.x)
            + bf_lo(g4.x) + bf_lo(g5.x) + bf_lo(g6.x) + bf_lo(g7.x);
        a1 += bf_hi(g0.x) + bf_hi(g1.x) + bf_hi(g2.x) + bf_hi(g3.x)
            + bf_hi(g4.x) + bf_hi(g5.x) + bf_hi(g6.x) + bf_hi(g7.x);
        a2 += bf_lo(g0.y) + bf_lo(g1.y) + bf_lo(g2.y) + bf_lo(g3.y)
            + bf_lo(g4.y) + bf_lo(g5.y) + bf_lo(g6.y) + bf_lo(g7.y);
        a3 += bf_hi(g0.y) + bf_hi(g1.y) + bf_hi(g2.y) + bf_hi(g3.y)
            + bf_hi(g4.y) + bf_hi(g5.y) + bf_hi(g6.y) + bf_hi(g7.y);
    }
    for (; e + 1 < e1; e += 2) {
        int s = ssrc[e + half];
        uint2 g = *(const uint2*)(Hs + (s << 7) + c);
        a0 += bf_lo(g.x); a1 += bf_hi(g.x);
        a2 += bf_lo(g.y); a3 += bf_hi(g.y);
    }
    if (e < e1) {  // single trailing edge: half 0 only
        int s = ssrc[e];
        uint2 g = *(const uint2*)(Hs + (s << 7) + c);
        float m = (half == 0) ? 1.f : 0.f;
        a0 = fmaf(bf_lo(g.x), m, a0); a1 = fmaf(bf_hi(g.x), m, a1);
        a2 = fmaf(bf_lo(g.y), m, a2); a3 = fmaf(bf_hi(g.y), m, a3);
    }
    a0 += __shfl_xor(a0, 32);
    a1 += __shfl_xor(a1, 32);
    a2 += __shfl_xor(a2, 32);
    a3 += __shfl_xor(a3, 32);
    if (half == 0) {
        float d = dinv[uw];
        uint2 o;
        o.x = (uint)f2bf(a0 * d) | ((uint)f2bf(a1 * d) << 16);
        o.y = (uint)f2bf(a2 * d) | ((uint)f2bf(a3 * d) << 16);
        *(uint2*)(out + uw * CH + c) = o;
    }
}

// ------ H = dinv*relu(Y*W + b) via MFMA bf16: Y [n][128], Wt [n][k] ------
__global__ __launch_bounds__(256) void k_gemm_mfma(const ushort* __restrict__ Y,
                                                   const ushort* __restrict__ Wt,
                                                   const float* __restrict__ bias,
                                                   const float* __restrict__ dinv,
                                                   ushort* __restrict__ H, int n) {
    __shared__ __align__(16) ushort As[128][136];   // +16B pad: 2-way banks (free)
    int tid = threadIdx.x;
    int r0 = blockIdx.x * 128;
#pragma unroll
    for (int i = 0; i < 8; i++) {
        int idx = tid + i * 256;          // 0..2047
        int row = idx >> 4;               // 0..127
        int c8 = (idx & 15) * 8;          // 0..120
        int r = r0 + row;
        uint4 v = make_uint4(0u, 0u, 0u, 0u);
        if (r < n) v = *(const uint4*)(Y + (size_t)r * CH + c8);
        *(uint4*)&As[row][c8] = v;
    }
    __syncthreads();
    int w = tid >> 6, lane = tid & 63;
    int qm = lane & 15, quad = lane >> 4;
    floatx4 acc[2][8];
#pragma unroll
    for (int mi = 0; mi < 2; mi++)
#pragma unroll
        for (int nt = 0; nt < 8; nt++) acc[mi][nt] = (floatx4){0.f, 0.f, 0.f, 0.f};
#pragma unroll
    for (int ks = 0; ks < 4; ks++) {
        int k0 = ks * 32 + quad * 8;
        short8 a0 = *(const short8*)&As[w * 32 + qm][k0];
        short8 a1 = *(const short8*)&As[w * 32 + 16 + qm][k0];
#pragma unroll
        for (int nt = 0; nt < 8; nt++) {
            short8 b = *(const short8*)(Wt + (nt * 16 + qm) * CH + k0);
            acc[0][nt] = __builtin_amdgcn_mfma_f32_16x16x32_bf16(a0, b, acc[0][nt], 0, 0, 0);
            acc[1][nt] = __builtin_amdgcn_mfma_f32_16x16x32_bf16(a1, b, acc[1][nt], 0, 0, 0);
        }
    }
#pragma unroll
    for (int mi = 0; mi < 2; mi++) {
#pragma unroll
        for (int reg = 0; reg < 4; reg++) {
            int r = r0 + w * 32 + mi * 16 + quad * 4 + reg;
            if (r >= n) continue;
            float d = dinv[r];
#pragma unroll
            for (int nt = 0; nt < 8; nt++) {
                int cidx = nt * 16 + qm;
                float val = fmaxf(acc[mi][nt][reg] + bias[cidx], 0.f) * d;
                H[(size_t)r * CH + cidx] = f2bf(val);
            }
        }
    }
}

// ---------------- mean pool over sorted batch ids (bf16 in, fp32 out) --------
__global__ __launch_bounds__(256) void k_pool(const ushort* __restrict__ Z,
                                              const int* __restrict__ batch,
                                              float* __restrict__ Q, int n) {
    int g = blockIdx.x;
    int lo = 0, hi = n;
    while (lo < hi) { int m = (lo + hi) >> 1; if (batch[m] < g) lo = m + 1; else hi = m; }
    int start = lo;
    lo = start; hi = n;
    while (lo < hi) { int m = (lo + hi) >> 1; if (batch[m] < g + 1) lo = m + 1; else hi = m; }
    int end = lo;
    int w = threadIdx.x >> 6, lane = threadIdx.x & 63;
    float a0 = 0.f, a1 = 0.f;
    for (int i = start + w; i < end; i += 4) {
        uint gv = *(const uint*)(Z + (size_t)i * CH + lane * 2);
        a0 += bf_lo(gv);
        a1 += bf_hi(gv);
    }
    __shared__ float red[4][128];
    red[w][lane * 2] = a0;
    red[w][lane * 2 + 1] = a1;
    __syncthreads();
    if (threadIdx.x < 128) {
        int t = threadIdx.x;
        float s = red[0][t] + red[1][t] + red[2][t] + red[3][t];
        float c = (float)(end - start);
        Q[g * CH + t] = s / fmaxf(c, 1.f);
    }
}

// ---------------- fold W2*Wfc, b2*Wfc+bfc ----------------
__global__ __launch_bounds__(256) void k_foldw(const float* __restrict__ W2,
                                               const float* __restrict__ b2,
                                               const float* __restrict__ Wfc,
                                               const float* __restrict__ bfc,
                                               float* __restrict__ Wc,
                                               float* __restrict__ bc) {
    int t = blockIdx.x * 256 + threadIdx.x;
    if (t < CH * OC) {
        int k = t >> 6, o = t & 63;
        float acc = 0.f;
        for (int j = 0; j < CH; j++) acc += W2[k * CH + j] * Wfc[j * OC + o];
        Wc[t] = acc;
    } else if (t < CH * OC + OC) {
        int o = t - CH * OC;
        float acc = bfc[o];
        for (int j = 0; j < CH; j++) acc += b2[j] * Wfc[j * OC + o];
        bc[o] = acc;
    }
}

// ---------------- out = Q*Wc + bc ----------------
__global__ __launch_bounds__(256) void k_out(const float* __restrict__ Q,
                                             const float* __restrict__ Wc,
                                             const float* __restrict__ bc,
                                             float* __restrict__ out) {
    int t = blockIdx.x * 256 + threadIdx.x;
    int g = t >> 6, o = t & 63;
    float acc = bc[o];
    for (int k = 0; k < CH; k++) acc += Q[g * CH + k] * Wc[k * OC + o];
    out[t] = acc;
}

extern "C" void kernel_launch(void* const* d_in, const int* in_sizes, int n_in,
                              void* d_out, int out_size, void* d_ws, size_t ws_size,
                              hipStream_t stream) {
    const float* x   = (const float*)d_in[0];
    const float* W1  = (const float*)d_in[1];
    const float* b1  = (const float*)d_in[2];
    const float* W2  = (const float*)d_in[3];
    const float* b2  = (const float*)d_in[4];
    const float* Wfc = (const float*)d_in[5];
    const float* bfc = (const float*)d_in[6];
    const int* edges = (const int*)d_in[7];
    const int* batch = (const int*)d_in[8];

    const int n = in_sizes[8];        // 100000
    const int E = in_sizes[7] / 2;    // 1600000
    const int* esrc = edges;
    const int* edst = edges + E;

    const int NB = (n + 255) >> 8;            // 391 coarse buckets
    const int T = NB * NBLK;
    const int chunk = (E + NBLK - 1) / NBLK;

    char* p = (char*)d_ws;
    auto carve = [&](size_t bytes) {
        void* r = (void*)p;
        p += (bytes + 255) & ~(size_t)255;
        return r;
    };
    int*    bhT       = (int*)carve((size_t)T * 4);   // bucket-major hist = scan in
    int*    off       = (int*)carve((size_t)T * 4);
    int*    bsums     = (int*)carve(512);
    int*    ebuf      = (int*)carve((size_t)E * 4);
    int*    row_start = (int*)carve((size_t)(n + 1) * 4);
    float*  dinv      = (float*)carve((size_t)n * 4);
    int*    ssrc      = (int*)carve((size_t)E * 4);
    ushort* xb        = (ushort*)carve((size_t)n * CH * 2);
    ushort* yb        = (ushort*)carve((size_t)n * CH * 2);
    ushort* Wt        = (ushort*)carve((size_t)CH * CH * 2);
    float*  q         = (float*)carve((size_t)NG * CH * 4);
    float*  Wc        = (float*)carve((size_t)CH * OC * 4);
    float*  bc        = (float*)carve((size_t)OC * 4);

    int nScanBlocks = (T + 1023) / 1024;

    // CSR build (atomic-free global ordering)
    k_hist<<<NBLK, 256, 0, stream>>>(edst, bhT, E, NB, chunk);
    k_scan1<<<nScanBlocks, 256, 0, stream>>>(bhT, off, bsums, T);
    k_scan2<<<1, 128, 0, stream>>>(bsums, nScanBlocks);
    k_scan3<<<(T + 255) / 256, 256, 0, stream>>>(off, bsums, T);
    k_part<<<NBLK, 256, 0, stream>>>(esrc, edst, off, ebuf, E, NB, chunk);
    k_csr<<<NB, 256, 0, stream>>>(ebuf, off, row_start, dinv, ssrc, n, NB, E);

    // features
    k_cvt<<<(n * CH / 4 + 255) / 256, 256, 0, stream>>>(x, dinv, xb, n * CH);
    k_cvtw<<<CH * CH / 256, 256, 0, stream>>>(W1, Wt);
    // y = dinv*(sum Xs + self)   (xb -> yb)
    k_agg<<<(n + 3) / 4, 256, 0, stream>>>(xb, row_start, ssrc, dinv, yb, n);
    // h1s = dinv*relu(y*W1 + b1)   (yb -> xb)
    k_gemm_mfma<<<(n + 127) / 128, 256, 0, stream>>>(yb, Wt, b1, dinv, xb, n);
    // z = dinv*(sum H1s + self)   (xb -> yb)
    k_agg<<<(n + 3) / 4, 256, 0, stream>>>(xb, row_start, ssrc, dinv, yb, n);
    // q = pool(z)
    k_pool<<<NG, 256, 0, stream>>>(yb, batch, q, n);
    // folded tail
    k_foldw<<<(CH * OC + OC + 255) / 256, 256, 0, stream>>>(W2, b2, Wfc, bfc, Wc, bc);
    k_out<<<(NG * OC + 255) / 256, 256, 0, stream>>>(q, Wc, bc, (float*)d_out);
}

// Round 6
// 333.260 us; speedup vs baseline: 1.0889x; 1.0889x over previous
//
#include <hip/hip_runtime.h>
#include <stdint.h>

#define NN 100000
#define NE 1600000
#define CH 128
#define OC 64
#define NG 512
#define NBLK 256      // partition blocks
#define NBMAX 4096    // max coarse buckets (nodes/256)
#define POOLB 400     // pool blocks

typedef unsigned int uint;
typedef unsigned short ushort;
typedef __attribute__((ext_vector_type(8))) short short8;
typedef __attribute__((ext_vector_type(4))) float floatx4;

__device__ __forceinline__ ushort f2bf(float f) {
    uint u = __float_as_uint(f);
    uint r = u + 0x7fffu + ((u >> 16) & 1u);  // round-to-nearest-even
    return (ushort)(r >> 16);
}
__device__ __forceinline__ float bf_lo(uint g) { return __uint_as_float(g << 16); }
__device__ __forceinline__ float bf_hi(uint g) { return __uint_as_float(g & 0xffff0000u); }

// ---------------- bucket histogram, written bucket-major ----------------
__global__ __launch_bounds__(256) void k_hist(const int* __restrict__ dst,
                                              int* __restrict__ bhT,
                                              int E, int NB, int chunk) {
    __shared__ int h[NBMAX];
    int blk = blockIdx.x, tid = threadIdx.x;
    for (int j = tid; j < NB; j += 256) h[j] = 0;
    __syncthreads();
    int lo = blk * chunk, hi = min(E, lo + chunk);
    for (int i = lo + tid; i < hi; i += 256) atomicAdd(&h[dst[i] >> 8], 1);
    __syncthreads();
    for (int j = tid; j < NB; j += 256) bhT[j * NBLK + blk] = h[j];
}

// ---------------- prefix scan (2-phase; block offsets folded by consumers) ---
__global__ __launch_bounds__(256) void k_scan1(const int* __restrict__ in,
                                               int* __restrict__ excl,
                                               int* __restrict__ bsums, int T) {
    __shared__ int sd[256];
    int tid = threadIdx.x;
    int base = blockIdx.x * 1024 + tid * 4;
    int v[4];
#pragma unroll
    for (int i = 0; i < 4; i++) v[i] = (base + i < T) ? in[base + i] : 0;
    int tsum = v[0] + v[1] + v[2] + v[3];
    int val = tsum;
    sd[tid] = val; __syncthreads();
    for (int off = 1; off < 256; off <<= 1) {
        int t = (tid >= off) ? sd[tid - off] : 0;
        __syncthreads();
        val += t; sd[tid] = val;
        __syncthreads();
    }
    int run = val - tsum;
#pragma unroll
    for (int i = 0; i < 4; i++) {
        if (base + i < T) excl[base + i] = run;
        run += v[i];
    }
    if (tid == 255) bsums[blockIdx.x] = val;
}

__global__ __launch_bounds__(128) void k_scan2(int* __restrict__ bs, int nb) {
    __shared__ int sd[128];
    int tid = threadIdx.x;
    int v = (tid < nb) ? bs[tid] : 0;
    int val = v;
    sd[tid] = val; __syncthreads();
    for (int off = 1; off < 128; off <<= 1) {
        int t = (tid >= off) ? sd[tid - off] : 0;
        __syncthreads();
        val += t; sd[tid] = val;
        __syncthreads();
    }
    if (tid < nb) bs[tid] = val - v;
}

// ------- partition: packed (src<<8)|(dst&255) into per-(bucket,block) segs ----
__global__ __launch_bounds__(256) void k_part(const int* __restrict__ src,
                                              const int* __restrict__ dst,
                                              const int* __restrict__ off,
                                              const int* __restrict__ boff,
                                              int* __restrict__ ebuf,
                                              int E, int NB, int chunk) {
    __shared__ int cur[NBMAX];
    int blk = blockIdx.x, tid = threadIdx.x;
    for (int j = tid; j < NB; j += 256) {
        int idx = j * NBLK + blk;
        cur[j] = off[idx] + boff[idx >> 10];
    }
    __syncthreads();
    int lo = blk * chunk, hi = min(E, lo + chunk);
    for (int i = lo + tid; i < hi; i += 256) {
        int s = src[i], d = dst[i];
        int pos = atomicAdd(&cur[d >> 8], 1);
        ebuf[pos] = (s << 8) | (d & 255);
    }
}

// ------- CSR finalize per bucket: deg, dinv, row_start, local scatter -------
__global__ __launch_bounds__(256) void k_csr(const int* __restrict__ ebuf,
                                             const int* __restrict__ off,
                                             const int* __restrict__ boff,
                                             int* __restrict__ row_start,
                                             float* __restrict__ dinv,
                                             int* __restrict__ ssrc,
                                             int n, int NB, int E) {
    __shared__ int cnt[256], sc[256], cur[256];
    int b = blockIdx.x, tid = threadIdx.x;
    int node0 = b << 8;
    int i0 = b * NBLK;
    int bstart = off[i0] + boff[i0 >> 10];
    int bend = E;
    if (b + 1 < NB) {
        int i1 = (b + 1) * NBLK;
        bend = off[i1] + boff[i1 >> 10];
    }
    cnt[tid] = 0;
    __syncthreads();
    for (int i = bstart + tid; i < bend; i += 256)
        atomicAdd(&cnt[ebuf[i] & 255], 1);
    __syncthreads();
    int v = cnt[tid];
    int val = v;
    sc[tid] = val; __syncthreads();
    for (int o = 1; o < 256; o <<= 1) {
        int t = (tid >= o) ? sc[tid - o] : 0;
        __syncthreads();
        val += t; sc[tid] = val;
        __syncthreads();
    }
    int excl = val - v;
    int node = node0 + tid;
    if (node < n) {
        row_start[node] = bstart + excl;
        dinv[node] = rsqrtf((float)v + 1.0f);
    }
    cur[tid] = bstart + excl;
    if (b == NB - 1 && tid == 0) row_start[n] = E;
    __syncthreads();
    for (int i = bstart + tid; i < bend; i += 256) {
        int e = ebuf[i];
        int pos = atomicAdd(&cur[e & 255], 1);
        ssrc[pos] = e >> 8;        // s < 2^23, sign-safe
    }
}

// ---------------- fp32 -> bf16 convert with dinv pre-scale ----------------
__global__ __launch_bounds__(256) void k_cvt(const float* __restrict__ x,
                                             const float* __restrict__ dinv,
                                             ushort* __restrict__ xb, int total) {
    int i = (blockIdx.x * 256 + threadIdx.x) * 4;
    if (i >= total) return;
    float d = dinv[i >> 7];
    float4 v = *(const float4*)(x + i);
    uint2 o;
    o.x = (uint)f2bf(v.x * d) | ((uint)f2bf(v.y * d) << 16);
    o.y = (uint)f2bf(v.z * d) | ((uint)f2bf(v.w * d) << 16);
    *(uint2*)(xb + i) = o;
}

// ------- fused prep: W1->Wt (bf16 transp) ; Wc=W2*Wfc ; bc=b2*Wfc+bfc -------
__global__ __launch_bounds__(256) void k_prep(const float* __restrict__ W1,
                                              const float* __restrict__ W2,
                                              const float* __restrict__ b2,
                                              const float* __restrict__ Wfc,
                                              const float* __restrict__ bfc,
                                              ushort* __restrict__ Wt,
                                              float* __restrict__ Wc,
                                              float* __restrict__ bc) {
    int t = blockIdx.x * 256 + threadIdx.x;
    if (t < CH * CH) {
        int nc = t >> 7, k = t & 127;
        Wt[nc * CH + k] = f2bf(W1[k * CH + nc]);
    } else if (t < CH * CH + CH * OC) {
        int u = t - CH * CH;
        int k = u >> 6, o = u & 63;
        float acc = 0.f;
        for (int j = 0; j < CH; j++) acc += W2[k * CH + j] * Wfc[j * OC + o];
        Wc[u] = acc;
    } else if (t < CH * CH + CH * OC + OC) {
        int o = t - CH * CH - CH * OC;
        float acc = bfc[o];
        for (int j = 0; j < CH; j++) acc += b2[j] * Wfc[j * OC + o];
        bc[o] = acc;
    }
}

// ------- aggregation v3: quarter-wave per edge, 16 rows in flight ----------
// out = dinv_dst * (sum_e Hs[src_e] + Hs[dst]); Hs pre-scaled by dinv.
__global__ __launch_bounds__(256) void k_agg(const ushort* __restrict__ Hs,
                                             const int* __restrict__ rs,
                                             const int* __restrict__ ssrc,
                                             const float* __restrict__ dinv,
                                             ushort* __restrict__ out, int n) {
    int wid = (blockIdx.x << 2) | (threadIdx.x >> 6);
    if (wid >= n) return;
    int uw = __builtin_amdgcn_readfirstlane(wid);
    int lane = threadIdx.x & 63;
    int sub = lane >> 4;          // edge slot within group of 4
    int li = lane & 15;
    int c = li * 8;               // 8 bf16 channels = 16 B per lane
    float a0 = 0.f, a1 = 0.f, a2 = 0.f, a3 = 0.f;
    float a4 = 0.f, a5 = 0.f, a6 = 0.f, a7 = 0.f;
    if (sub == 0) {
        uint4 sv = *(const uint4*)(Hs + ((size_t)uw << 7) + c);
        a0 = bf_lo(sv.x); a1 = bf_hi(sv.x);
        a2 = bf_lo(sv.y); a3 = bf_hi(sv.y);
        a4 = bf_lo(sv.z); a5 = bf_hi(sv.z);
        a6 = bf_lo(sv.w); a7 = bf_hi(sv.w);
    }
    int e0 = rs[uw], e1 = rs[uw + 1];
    if (e0 < e1) {
        int e1m = e1 - 1;
        for (int e = e0; e < e1; e += 16) {
            int i0 = e + sub, i1 = e + 4 + sub, i2 = e + 8 + sub, i3 = e + 12 + sub;
            int s0 = ssrc[min(i0, e1m)];
            int s1 = ssrc[min(i1, e1m)];
            int s2 = ssrc[min(i2, e1m)];
            int s3 = ssrc[min(i3, e1m)];
            uint4 g0 = *(const uint4*)(Hs + (s0 << 7) + c);
            uint4 g1 = *(const uint4*)(Hs + (s1 << 7) + c);
            uint4 g2 = *(const uint4*)(Hs + (s2 << 7) + c);
            uint4 g3 = *(const uint4*)(Hs + (s3 << 7) + c);
            float m0 = (i0 < e1) ? 1.f : 0.f;
            float m1 = (i1 < e1) ? 1.f : 0.f;
            float m2 = (i2 < e1) ? 1.f : 0.f;
            float m3 = (i3 < e1) ? 1.f : 0.f;
            a0 = fmaf(bf_lo(g0.x), m0, a0); a1 = fmaf(bf_hi(g0.x), m0, a1);
            a2 = fmaf(bf_lo(g0.y), m0, a2); a3 = fmaf(bf_hi(g0.y), m0, a3);
            a4 = fmaf(bf_lo(g0.z), m0, a4); a5 = fmaf(bf_hi(g0.z), m0, a5);
            a6 = fmaf(bf_lo(g0.w), m0, a6); a7 = fmaf(bf_hi(g0.w), m0, a7);
            a0 = fmaf(bf_lo(g1.x), m1, a0); a1 = fmaf(bf_hi(g1.x), m1, a1);
            a2 = fmaf(bf_lo(g1.y), m1, a2); a3 = fmaf(bf_hi(g1.y), m1, a3);
            a4 = fmaf(bf_lo(g1.z), m1, a4); a5 = fmaf(bf_hi(g1.z), m1, a5);
            a6 = fmaf(bf_lo(g1.w), m1, a6); a7 = fmaf(bf_hi(g1.w), m1, a7);
            a0 = fmaf(bf_lo(g2.x), m2, a0); a1 = fmaf(bf_hi(g2.x), m2, a1);
            a2 = fmaf(bf_lo(g2.y), m2, a2); a3 = fmaf(bf_hi(g2.y), m2, a3);
            a4 = fmaf(bf_lo(g2.z), m2, a4); a5 = fmaf(bf_hi(g2.z), m2, a5);
            a6 = fmaf(bf_lo(g2.w), m2, a6); a7 = fmaf(bf_hi(g2.w), m2, a7);
            a0 = fmaf(bf_lo(g3.x), m3, a0); a1 = fmaf(bf_hi(g3.x), m3, a1);
            a2 = fmaf(bf_lo(g3.y), m3, a2); a3 = fmaf(bf_hi(g3.y), m3, a3);
            a4 = fmaf(bf_lo(g3.z), m3, a4); a5 = fmaf(bf_hi(g3.z), m3, a5);
            a6 = fmaf(bf_lo(g3.w), m3, a6); a7 = fmaf(bf_hi(g3.w), m3, a7);
        }
    }
    a0 += __shfl_xor(a0, 16); a0 += __shfl_xor(a0, 32);
    a1 += __shfl_xor(a1, 16); a1 += __shfl_xor(a1, 32);
    a2 += __shfl_xor(a2, 16); a2 += __shfl_xor(a2, 32);
    a3 += __shfl_xor(a3, 16); a3 += __shfl_xor(a3, 32);
    a4 += __shfl_xor(a4, 16); a4 += __shfl_xor(a4, 32);
    a5 += __shfl_xor(a5, 16); a5 += __shfl_xor(a5, 32);
    a6 += __shfl_xor(a6, 16); a6 += __shfl_xor(a6, 32);
    a7 += __shfl_xor(a7, 16); a7 += __shfl_xor(a7, 32);
    if (sub == 0) {
        float d = dinv[uw];
        uint4 o;
        o.x = (uint)f2bf(a0 * d) | ((uint)f2bf(a1 * d) << 16);
        o.y = (uint)f2bf(a2 * d) | ((uint)f2bf(a3 * d) << 16);
        o.z = (uint)f2bf(a4 * d) | ((uint)f2bf(a5 * d) << 16);
        o.w = (uint)f2bf(a6 * d) | ((uint)f2bf(a7 * d) << 16);
        *(uint4*)(out + ((size_t)uw << 7) + c) = o;
    }
}

// ------ H = dinv*relu(Y*W + b) via MFMA bf16: Y [n][128], Wt [n][k] ------
__global__ __launch_bounds__(256) void k_gemm_mfma(const ushort* __restrict__ Y,
                                                   const ushort* __restrict__ Wt,
                                                   const float* __restrict__ bias,
                                                   const float* __restrict__ dinv,
                                                   ushort* __restrict__ H, int n) {
    __shared__ __align__(16) ushort As[128][136];
    int tid = threadIdx.x;
    int r0 = blockIdx.x * 128;
#pragma unroll
    for (int i = 0; i < 8; i++) {
        int idx = tid + i * 256;
        int row = idx >> 4;
        int c8 = (idx & 15) * 8;
        int r = r0 + row;
        uint4 v = make_uint4(0u, 0u, 0u, 0u);
        if (r < n) v = *(const uint4*)(Y + (size_t)r * CH + c8);
        *(uint4*)&As[row][c8] = v;
    }
    __syncthreads();
    int w = tid >> 6, lane = tid & 63;
    int qm = lane & 15, quad = lane >> 4;
    floatx4 acc[2][8];
#pragma unroll
    for (int mi = 0; mi < 2; mi++)
#pragma unroll
        for (int nt = 0; nt < 8; nt++) acc[mi][nt] = (floatx4){0.f, 0.f, 0.f, 0.f};
#pragma unroll
    for (int ks = 0; ks < 4; ks++) {
        int k0 = ks * 32 + quad * 8;
        short8 va0 = *(const short8*)&As[w * 32 + qm][k0];
        short8 va1 = *(const short8*)&As[w * 32 + 16 + qm][k0];
#pragma unroll
        for (int nt = 0; nt < 8; nt++) {
            short8 b = *(const short8*)(Wt + (nt * 16 + qm) * CH + k0);
            acc[0][nt] = __builtin_amdgcn_mfma_f32_16x16x32_bf16(va0, b, acc[0][nt], 0, 0, 0);
            acc[1][nt] = __builtin_amdgcn_mfma_f32_16x16x32_bf16(va1, b, acc[1][nt], 0, 0, 0);
        }
    }
#pragma unroll
    for (int mi = 0; mi < 2; mi++) {
#pragma unroll
        for (int reg = 0; reg < 4; reg++) {
            int r = r0 + w * 32 + mi * 16 + quad * 4 + reg;
            if (r >= n) continue;
            float d = dinv[r];
#pragma unroll
            for (int nt = 0; nt < 8; nt++) {
                int cidx = nt * 16 + qm;
                float val = fmaxf(acc[mi][nt][reg] + bias[cidx], 0.f) * d;
                H[(size_t)r * CH + cidx] = f2bf(val);
            }
        }
    }
}

// -------- pool: node-range sweep, per-graph flush with fp32 atomics ---------
__global__ __launch_bounds__(256) void k_pool(const ushort* __restrict__ Z,
                                              const int* __restrict__ batch,
                                              float* __restrict__ Qs,
                                              float* __restrict__ cnt,
                                              int n, int npb) {
    int lo = blockIdx.x * npb;
    if (lo >= n) return;
    int hi = min(n, lo + npb);
    int w = threadIdx.x >> 6, lane = threadIdx.x & 63;
    int c = lane * 2;
    float a0 = 0.f, a1 = 0.f;
    int curg = -1, rc = 0;
    for (int i = lo + w; i < hi; i += 4) {
        int g = batch[i];
        if (g != curg) {
            if (rc > 0) {
                atomicAdd(&Qs[curg * CH + c], a0);
                atomicAdd(&Qs[curg * CH + c + 1], a1);
                if (lane == 0) atomicAdd(&cnt[curg], (float)rc);
            }
            curg = g; a0 = a1 = 0.f; rc = 0;
        }
        uint v = *(const uint*)(Z + (size_t)i * CH + c);
        a0 += bf_lo(v); a1 += bf_hi(v); rc++;
    }
    if (rc > 0) {
        atomicAdd(&Qs[curg * CH + c], a0);
        atomicAdd(&Qs[curg * CH + c + 1], a1);
        if (lane == 0) atomicAdd(&cnt[curg], (float)rc);
    }
}

// ---------------- out = (Qs/cnt)*Wc + bc ----------------
__global__ __launch_bounds__(256) void k_out(const float* __restrict__ Qs,
                                             const float* __restrict__ cnt,
                                             const float* __restrict__ Wc,
                                             const float* __restrict__ bc,
                                             float* __restrict__ out) {
    int t = blockIdx.x * 256 + threadIdx.x;
    int g = t >> 6, o = t & 63;
    float invc = 1.f / fmaxf(cnt[g], 1.f);
    float acc = 0.f;
    for (int k = 0; k < CH; k++) acc += Qs[g * CH + k] * Wc[k * OC + o];
    out[t] = acc * invc + bc[o];
}

extern "C" void kernel_launch(void* const* d_in, const int* in_sizes, int n_in,
                              void* d_out, int out_size, void* d_ws, size_t ws_size,
                              hipStream_t stream) {
    const float* x   = (const float*)d_in[0];
    const float* W1  = (const float*)d_in[1];
    const float* b1  = (const float*)d_in[2];
    const float* W2  = (const float*)d_in[3];
    const float* b2  = (const float*)d_in[4];
    const float* Wfc = (const float*)d_in[5];
    const float* bfc = (const float*)d_in[6];
    const int* edges = (const int*)d_in[7];
    const int* batch = (const int*)d_in[8];

    const int n = in_sizes[8];        // 100000
    const int E = in_sizes[7] / 2;    // 1600000
    const int* esrc = edges;
    const int* edst = edges + E;

    const int NB = (n + 255) >> 8;            // 391 coarse buckets
    const int T = NB * NBLK;
    const int chunk = (E + NBLK - 1) / NBLK;

    char* p = (char*)d_ws;
    auto carve = [&](size_t bytes) {
        void* r = (void*)p;
        p += (bytes + 255) & ~(size_t)255;
        return r;
    };
    int*    bhT       = (int*)carve((size_t)T * 4);
    int*    off       = (int*)carve((size_t)T * 4);
    int*    bsums     = (int*)carve(512);
    int*    ebuf      = (int*)carve((size_t)E * 4);
    int*    row_start = (int*)carve((size_t)(n + 1) * 4);
    float*  dinv      = (float*)carve((size_t)n * 4);
    int*    ssrc      = (int*)carve((size_t)E * 4);
    ushort* xb        = (ushort*)carve((size_t)n * CH * 2);
    ushort* yb        = (ushort*)carve((size_t)n * CH * 2);
    ushort* Wt        = (ushort*)carve((size_t)CH * CH * 2);
    float*  q         = (float*)carve((size_t)NG * CH * 4);
    float*  cnt       = (float*)carve((size_t)NG * 4);
    float*  Wc        = (float*)carve((size_t)CH * OC * 4);
    float*  bc        = (float*)carve((size_t)OC * 4);

    int nScanBlocks = (T + 1023) / 1024;
    int npb = (n + POOLB - 1) / POOLB;

    hipMemsetAsync(q, 0, (size_t)(NG * CH + NG) * 4, stream);

    // CSR build (atomic-free global ordering)
    k_hist<<<NBLK, 256, 0, stream>>>(edst, bhT, E, NB, chunk);
    k_scan1<<<nScanBlocks, 256, 0, stream>>>(bhT, off, bsums, T);
    k_scan2<<<1, 128, 0, stream>>>(bsums, nScanBlocks);
    k_part<<<NBLK, 256, 0, stream>>>(esrc, edst, off, bsums, ebuf, E, NB, chunk);
    k_csr<<<NB, 256, 0, stream>>>(ebuf, off, bsums, row_start, dinv, ssrc, n, NB, E);

    // features + weight prep
    k_cvt<<<(n * CH / 4 + 255) / 256, 256, 0, stream>>>(x, dinv, xb, n * CH);
    k_prep<<<(CH * CH + CH * OC + OC + 255) / 256, 256, 0, stream>>>(
        W1, W2, b2, Wfc, bfc, Wt, Wc, bc);
    // y = dinv*(sum Xs + self)   (xb -> yb)
    k_agg<<<(n + 3) / 4, 256, 0, stream>>>(xb, row_start, ssrc, dinv, yb, n);
    // h1s = dinv*relu(y*W1 + b1)   (yb -> xb)
    k_gemm_mfma<<<(n + 127) / 128, 256, 0, stream>>>(yb, Wt, b1, dinv, xb, n);
    // z = dinv*(sum H1s + self)   (xb -> yb)
    k_agg<<<(n + 3) / 4, 256, 0, stream>>>(xb, row_start, ssrc, dinv, yb, n);
    // q = sum-pool(z), cnt via atomics
    k_pool<<<POOLB, 256, 0, stream>>>(yb, batch, q, cnt, n, npb);
    // out = (q/cnt)*Wc + bc
    k_out<<<(NG * OC + 255) / 256, 256, 0, stream>>>(q, cnt, Wc, bc, (float*)d_out);
}